// Round 4
// baseline (751.428 us; speedup 1.0000x reference)
//
#include <hip/hip_runtime.h>
#include <math.h>

#define NPTS 16384
#define DIN 13
#define KNN 8

typedef _Float16 half8 __attribute__((ext_vector_type(8)));
typedef float f32x4 __attribute__((ext_vector_type(4)));

union HU { uint4 u; half8 h; };

__device__ __forceinline__ float silu(float v) {
    return v / (1.0f + __expf(-v));
}

// monotone float<->uint order maps (for LDS atomicMin thresholds)
__device__ __forceinline__ unsigned fmap(float f) {
    unsigned u = __float_as_uint(f);
    return u ^ (((unsigned)((int)u >> 31)) | 0x80000000u);
}
__device__ __forceinline__ float funmap(unsigned m) {
    unsigned msk = ((unsigned)((int)(~m) >> 31)) | 0x80000000u;
    return __uint_as_float(m ^ msk);
}

// branchless insert of (v,j) into sorted-asc dist[8]/id[8] (self-predicating)
__device__ __forceinline__ void ins8(float v, int j, float* dist, int* id) {
    bool c[KNN];
#pragma unroll
    for (int k = 0; k < KNN; ++k) c[k] = v < dist[k];
#pragma unroll
    for (int k = KNN - 1; k >= 1; --k) {
        id[k] = c[k - 1] ? id[k - 1] : (c[k] ? j : id[k]);
        dist[k] = fminf(fmaxf(v, dist[k - 1]), dist[k]);
    }
    id[0] = c[0] ? j : id[0];
    dist[0] = fminf(v, dist[0]);
}

// values-only insert
__device__ __forceinline__ void ins8v(float v, float* dist) {
#pragma unroll
    for (int k = KNN - 1; k >= 1; --k)
        dist[k] = fminf(fmaxf(v, dist[k - 1]), dist[k]);
    dist[0] = fminf(v, dist[0]);
}

// merge my sorted-asc a[8] with partner (lane^mask)'s: keep 8 smallest, sorted
__device__ __forceinline__ void mergeTop8(float* a, int mask) {
    float b[8];
#pragma unroll
    for (int k = 0; k < 8; ++k) b[k] = __shfl_xor(a[k], mask, 64);
    float m[8];
#pragma unroll
    for (int k = 0; k < 8; ++k) m[k] = fminf(a[k], b[7 - k]);  // bitonic
#define CSW(p, q) { float lo = fminf(m[p], m[q]); float hi = fmaxf(m[p], m[q]); m[p] = lo; m[q] = hi; }
    CSW(0,4) CSW(1,5) CSW(2,6) CSW(3,7)
    CSW(0,2) CSW(1,3) CSW(4,6) CSW(5,7)
    CSW(0,1) CSW(2,3) CSW(4,5) CSW(6,7)
#undef CSW
#pragma unroll
    for (int k = 0; k < 8; ++k) a[k] = m[k];
}

// ---------------- K1: encoder MLP -> x, fp16-split arrays ----------------
__global__ __launch_bounds__(256) void k_encoder(
    const float* __restrict__ x_pfc,
    const float* __restrict__ W1, const float* __restrict__ b1,
    const float* __restrict__ W2, const float* __restrict__ b2,
    const float* __restrict__ W3, const float* __restrict__ b3,
    float* __restrict__ xo, _Float16* __restrict__ HL,
    _Float16* __restrict__ YH, _Float16* __restrict__ YL,
    _Float16* __restrict__ SQ2)
{
    __shared__ float sW1[DIN * 8];
    __shared__ float sb1[8];
    __shared__ float sW2[8 * 16];
    __shared__ float sb2[16];
    __shared__ float sW3[16 * 15];
    __shared__ float sb3[15];
    int t = threadIdx.x;
    for (int q = t; q < DIN * 8; q += 256) sW1[q] = W1[q];
    for (int q = t; q < 8; q += 256) sb1[q] = b1[q];
    for (int q = t; q < 8 * 16; q += 256) sW2[q] = W2[q];
    for (int q = t; q < 16; q += 256) sb2[q] = b2[q];
    for (int q = t; q < 16 * 15; q += 256) sW3[q] = W3[q];
    for (int q = t; q < 15; q += 256) sb3[q] = b3[q];
    __syncthreads();

    int i = blockIdx.x * 256 + t;
    float in[DIN];
#pragma unroll
    for (int d = 0; d < DIN; ++d) in[d] = x_pfc[i * DIN + d];

    float a1[8];
#pragma unroll
    for (int h = 0; h < 8; ++h) a1[h] = sb1[h];
#pragma unroll
    for (int d = 0; d < DIN; ++d) {
        float v = in[d];
#pragma unroll
        for (int h = 0; h < 8; ++h) a1[h] += v * sW1[d * 8 + h];
    }
#pragma unroll
    for (int h = 0; h < 8; ++h) a1[h] = silu(a1[h]);

    float a2[16];
#pragma unroll
    for (int h = 0; h < 16; ++h) a2[h] = sb2[h];
#pragma unroll
    for (int d = 0; d < 8; ++d) {
        float v = a1[d];
#pragma unroll
        for (int h = 0; h < 16; ++h) a2[h] += v * sW2[d * 16 + h];
    }
#pragma unroll
    for (int h = 0; h < 16; ++h) a2[h] = silu(a2[h]);

    float a3[15];
#pragma unroll
    for (int h = 0; h < 15; ++h) a3[h] = sb3[h];
#pragma unroll
    for (int d = 0; d < 16; ++d) {
        float v = a2[d];
#pragma unroll
        for (int h = 0; h < 15; ++h) a3[h] += v * sW3[d * 15 + h];
    }

    float xr[16];
#pragma unroll
    for (int h = 0; h < 15; ++h) xr[h] = a3[h];
    xr[15] = in[DIN - 1];

    float s = 0.0f;
#pragma unroll
    for (int d = 0; d < 16; ++d) s += xr[d] * xr[d];

#pragma unroll
    for (int d = 0; d < 16; ++d) {
        xo[i * 16 + d] = xr[d];
        _Float16 h = (_Float16)xr[d];
        _Float16 l = (_Float16)(xr[d] - (float)h);
        HL[(size_t)i * 32 + d] = h;
        HL[(size_t)i * 32 + 16 + d] = l;
        float y = -2.0f * xr[d];
        _Float16 yh = (_Float16)y;
        _Float16 yl = (_Float16)(y - (float)yh);
        YH[(size_t)i * 16 + d] = yh;
        YL[(size_t)i * 16 + d] = yl;
    }
    _Float16 sh = (_Float16)s;
    SQ2[(size_t)i * 2] = sh;
    SQ2[(size_t)i * 2 + 1] = (_Float16)(s - (float)sh);
}

// ---------------- K2: MFMA KNN top-8 ----------------
// Block = 512 threads (8 waves), i-tile of 32 (2 subtiles of 16 cols).
// Wave w scans j in [w*2048,(w+1)*2048) in 16-j tiles. Per tile & subtile:
//   C = mfma(A2,B2, mfma(A1,B1,0))  where A1=[h,l], B1=[yh,yh],
//   A2=[h | sqh,sql,0..], B2=[yl | 1,1,0..]  => C = sq[j] - 2*x_i.x_j
// Selection: per-lane top-8 (v,id) for its column i, filtered by a shared
// per-i LDS threshold (any lane's running 8th upper-bounds global kth).
__global__ __launch_bounds__(512, 4) void k_knn(
    const _Float16* __restrict__ HL, const _Float16* __restrict__ YH,
    const _Float16* __restrict__ YL, const _Float16* __restrict__ SQ2,
    int* __restrict__ knn_idx)
{
    __shared__ unsigned thrU[32];
    __shared__ float wl[8 * 8 * 32];   // [k][w][ilocal]
    __shared__ float kthv[32];
    __shared__ int cnt[32];
    __shared__ int cand[32 * 16];

    int t = threadIdx.x;
    int w = t >> 6;
    int lane = t & 63;
    int m = lane & 15;
    int kq = lane >> 4;
    int i0 = blockIdx.x * 32;

    if (t < 32) { thrU[t] = 0xFFFFFFFFu; cnt[t] = 0; }
    __syncthreads();

    // B fragments (once per wave): B[k][n]: n=lane&15, k=(lane>>4)*8+b
    half8 B1[2], B2[2];
#pragma unroll
    for (int s = 0; s < 2; ++s) {
        int gi = i0 + s * 16 + m;
        B1[s] = *(const half8*)(YH + (size_t)gi * 16 + (kq & 1) * 8);
        half8 b2l = *(const half8*)(YL + (size_t)gi * 16 + ((kq < 2) ? kq * 8 : 0));
        HU b2u; b2u.h = b2l;
        HU r;
        r.u.x = (kq < 2) ? b2u.u.x : ((kq == 2) ? 0x3C003C00u : 0u);
        r.u.y = (kq < 2) ? b2u.u.y : 0u;
        r.u.z = (kq < 2) ? b2u.u.z : 0u;
        r.u.w = (kq < 2) ? b2u.u.w : 0u;
        B2[s] = r.h;
    }

    float dist[2][8];
    int idl[2][8];
#pragma unroll
    for (int s = 0; s < 2; ++s)
#pragma unroll
        for (int k = 0; k < 8; ++k) { dist[s][k] = 3.4e38f; idl[s][k] = -1; }

    const _Float16* aptr = HL + ((size_t)(w * 2048 + m)) * 32 + kq * 8;
    const unsigned* sqptr = (const unsigned*)SQ2 + (w * 2048 + m);
    int jbase = w * 2048 + kq * 4;

    volatile unsigned* thrV = thrU;

    for (int tt = 0; tt < 128; ++tt) {
        half8 a1 = *(const half8*)aptr;
        unsigned sqd = *sqptr;
        HU a1u; a1u.h = a1;
        HU a2u;
        a2u.u.x = (kq < 2) ? a1u.u.x : ((kq == 2) ? sqd : 0u);
        a2u.u.y = (kq < 2) ? a1u.u.y : 0u;
        a2u.u.z = (kq < 2) ? a1u.u.z : 0u;
        a2u.u.w = (kq < 2) ? a1u.u.w : 0u;
        half8 a2 = a2u.h;

        f32x4 c0 = {0.f, 0.f, 0.f, 0.f};
        f32x4 c1 = {0.f, 0.f, 0.f, 0.f};
        c0 = __builtin_amdgcn_mfma_f32_16x16x32_f16(a2, B2[0], c0, 0, 0, 0);
        c0 = __builtin_amdgcn_mfma_f32_16x16x32_f16(a1, B1[0], c0, 0, 0, 0);
        c1 = __builtin_amdgcn_mfma_f32_16x16x32_f16(a2, B2[1], c1, 0, 0, 0);
        c1 = __builtin_amdgcn_mfma_f32_16x16x32_f16(a1, B1[1], c1, 0, 0, 0);

        float th0 = funmap(thrV[m]);
        float th1 = funmap(thrV[16 + m]);
        int jr = jbase + tt * 16;

        float mn0 = fminf(fminf(c0.x, c0.y), fminf(c0.z, c0.w));
        if (__any(mn0 <= th0)) {
            if (__any(c0.x <= th0)) ins8(c0.x, jr + 0, dist[0], idl[0]);
            if (__any(c0.y <= th0)) ins8(c0.y, jr + 1, dist[0], idl[0]);
            if (__any(c0.z <= th0)) ins8(c0.z, jr + 2, dist[0], idl[0]);
            if (__any(c0.w <= th0)) ins8(c0.w, jr + 3, dist[0], idl[0]);
        }
        float mn1 = fminf(fminf(c1.x, c1.y), fminf(c1.z, c1.w));
        if (__any(mn1 <= th1)) {
            if (__any(c1.x <= th1)) ins8(c1.x, jr + 0, dist[1], idl[1]);
            if (__any(c1.y <= th1)) ins8(c1.y, jr + 1, dist[1], idl[1]);
            if (__any(c1.z <= th1)) ins8(c1.z, jr + 2, dist[1], idl[1]);
            if (__any(c1.w <= th1)) ins8(c1.w, jr + 3, dist[1], idl[1]);
        }

        if ((tt & 3) == 3) {
            atomicMin(&thrU[m], fmap(dist[0][7]));
            atomicMin(&thrU[16 + m], fmap(dist[1][7]));
        }
        aptr += 16 * 32;
        sqptr += 16;
    }

    // Phase A: in-wave value merges (4 lanes per (s,i) -> one sorted-8)
#pragma unroll
    for (int s = 0; s < 2; ++s) {
        float va[8];
#pragma unroll
        for (int k = 0; k < 8; ++k) va[k] = dist[s][k];
        mergeTop8(va, 16);
        mergeTop8(va, 32);
        if (kq == 0) {
#pragma unroll
            for (int k = 0; k < 8; ++k)
                wl[(k * 8 + w) * 32 + s * 16 + m] = va[k];
        }
    }
    __syncthreads();

    // Phase B: exact global kth per i (wave 0, 32 lanes)
    if (t < 32) {
        float fd[8];
#pragma unroll
        for (int k = 0; k < 8; ++k) fd[k] = 3.4e38f;
        for (int w2 = 0; w2 < 8; ++w2)
#pragma unroll
            for (int k = 0; k < 8; ++k)
                ins8v(wl[(k * 8 + w2) * 32 + t], fd);
        kthv[t] = fd[7];
    }
    __syncthreads();

    // Phase C: append ids of values <= kth
#pragma unroll
    for (int s = 0; s < 2; ++s) {
        float kv = kthv[s * 16 + m];
#pragma unroll
        for (int k = 0; k < 8; ++k) {
            if (dist[s][k] <= kv) {
                int p = atomicAdd(&cnt[s * 16 + m], 1);
                if (p < 16) cand[(s * 16 + m) * 16 + p] = idl[s][k];
            }
        }
    }
    __syncthreads();

    if (t < 32) {
#pragma unroll
        for (int k = 0; k < 8; ++k)
            knn_idx[(size_t)(i0 + t) * 8 + k] = cand[t * 16 + k];
    }
}

// ---------------- K3: edge conv + head MLP + output concat ----------------
__global__ __launch_bounds__(256) void k_head(
    const float* __restrict__ x, const int* __restrict__ knn_idx,
    const float* __restrict__ x_pfc,
    const float* __restrict__ We, const float* __restrict__ be,
    const float* __restrict__ Wf1, const float* __restrict__ bf1,
    const float* __restrict__ Wf2, const float* __restrict__ bf2,
    float* __restrict__ out)
{
    __shared__ float sWe[32 * 16];
    __shared__ float sbe[16];
    __shared__ float sWf1[16 * 32];
    __shared__ float sbf1[32];
    __shared__ float sWf2[32 * 16];
    __shared__ float sbf2[16];
    int t = threadIdx.x;
    for (int q = t; q < 32 * 16; q += 256) sWe[q] = We[q];
    for (int q = t; q < 16; q += 256) sbe[q] = be[q];
    for (int q = t; q < 16 * 32; q += 256) sWf1[q] = Wf1[q];
    for (int q = t; q < 32; q += 256) sbf1[q] = bf1[q];
    for (int q = t; q < 32 * 16; q += 256) sWf2[q] = Wf2[q];
    for (int q = t; q < 16; q += 256) sbf2[q] = bf2[q];
    __syncthreads();

    int i = blockIdx.x * 256 + t;
    float xi[16];
#pragma unroll
    for (int d = 0; d < 16; ++d) xi[d] = x[i * 16 + d];

    float accb[16];
#pragma unroll
    for (int h = 0; h < 16; ++h) accb[h] = sbe[h];
#pragma unroll
    for (int d = 0; d < 16; ++d) {
        float v = xi[d];
#pragma unroll
        for (int h = 0; h < 16; ++h) accb[h] += v * sWe[d * 16 + h];
    }

    float feats[16];
#pragma unroll
    for (int h = 0; h < 16; ++h) feats[h] = 0.0f;

    for (int e = 0; e < KNN; ++e) {
        int j = knn_idx[i * KNN + e];
        float xd[16];
        const float4* xjv = (const float4*)(x + (size_t)j * 16);
#pragma unroll
        for (int q = 0; q < 4; ++q) {
            float4 v = xjv[q];
            xd[q * 4 + 0] = v.x - xi[q * 4 + 0];
            xd[q * 4 + 1] = v.y - xi[q * 4 + 1];
            xd[q * 4 + 2] = v.z - xi[q * 4 + 2];
            xd[q * 4 + 3] = v.w - xi[q * 4 + 3];
        }
        float acc[16];
#pragma unroll
        for (int h = 0; h < 16; ++h) acc[h] = accb[h];
#pragma unroll
        for (int d = 0; d < 16; ++d) {
            float v = xd[d];
#pragma unroll
            for (int h = 0; h < 16; ++h) acc[h] += v * sWe[(16 + d) * 16 + h];
        }
#pragma unroll
        for (int h = 0; h < 16; ++h) feats[h] += silu(acc[h]);
    }
#pragma unroll
    for (int h = 0; h < 16; ++h) feats[h] *= (1.0f / KNN);

    float f1[32];
#pragma unroll
    for (int h = 0; h < 32; ++h) f1[h] = sbf1[h];
#pragma unroll
    for (int k = 0; k < 16; ++k) {
        float v = feats[k];
#pragma unroll
        for (int h = 0; h < 32; ++h) f1[h] += v * sWf1[k * 32 + h];
    }
#pragma unroll
    for (int h = 0; h < 32; ++h) f1[h] = silu(f1[h]);

    float f2[16];
#pragma unroll
    for (int h = 0; h < 16; ++h) f2[h] = sbf2[h];
#pragma unroll
    for (int k = 0; k < 32; ++k) {
        float v = f1[k];
#pragma unroll
        for (int h = 0; h < 16; ++h) f2[h] += v * sWf2[k * 16 + h];
    }

#pragma unroll
    for (int h = 0; h < 16; ++h) out[(size_t)i * 29 + h] = f2[h];
#pragma unroll
    for (int d = 0; d < DIN; ++d) out[(size_t)i * 29 + 16 + d] = x_pfc[i * DIN + d];
}

extern "C" void kernel_launch(void* const* d_in, const int* in_sizes, int n_in,
                              void* d_out, int out_size, void* d_ws, size_t ws_size,
                              hipStream_t stream)
{
    const float* x_pfc = (const float*)d_in[0];
    const float* W1 = (const float*)d_in[1];
    const float* b1 = (const float*)d_in[2];
    const float* W2 = (const float*)d_in[3];
    const float* b2 = (const float*)d_in[4];
    const float* W3 = (const float*)d_in[5];
    const float* b3 = (const float*)d_in[6];
    const float* We = (const float*)d_in[7];
    const float* be = (const float*)d_in[8];
    const float* Wf1 = (const float*)d_in[9];
    const float* bf1 = (const float*)d_in[10];
    const float* Wf2 = (const float*)d_in[11];
    const float* bf2 = (const float*)d_in[12];
    float* out = (float*)d_out;

    float* xw = (float*)d_ws;                       // N*16 f32
    int* idxw = (int*)(xw + (size_t)NPTS * 16);     // N*8 int
    _Float16* HLa = (_Float16*)(idxw + (size_t)NPTS * 8);  // N*32
    _Float16* YHa = HLa + (size_t)NPTS * 32;        // N*16
    _Float16* YLa = YHa + (size_t)NPTS * 16;        // N*16
    _Float16* SQ2a = YLa + (size_t)NPTS * 16;       // N*2

    hipLaunchKernelGGL(k_encoder, dim3(NPTS / 256), dim3(256), 0, stream,
                       x_pfc, W1, b1, W2, b2, W3, b3, xw, HLa, YHa, YLa, SQ2a);
    hipLaunchKernelGGL(k_knn, dim3(NPTS / 32), dim3(512), 0, stream,
                       HLa, YHa, YLa, SQ2a, idxw);
    hipLaunchKernelGGL(k_head, dim3(NPTS / 256), dim3(256), 0, stream,
                       xw, idxw, x_pfc, We, be, Wf1, bf1, Wf2, bf2, out);
}

// Round 5
// 331.940 us; speedup vs baseline: 2.2637x; 2.2637x over previous
//
#include <hip/hip_runtime.h>
#include <math.h>

#define NPTS 16384
#define DIN 13
#define KNN 8

typedef _Float16 half8 __attribute__((ext_vector_type(8)));
typedef float f32x4 __attribute__((ext_vector_type(4)));

union HU { uint4 u; half8 h; };

__device__ __forceinline__ float silu(float v) {
    return v / (1.0f + __expf(-v));
}

// branchless scalar top-8 insert (sorted ascending d0..d7), 8 med3-class ops
#define INS8V(v) {                      \
    d7 = fminf(fmaxf((v), d6), d7);     \
    d6 = fminf(fmaxf((v), d5), d6);     \
    d5 = fminf(fmaxf((v), d4), d5);     \
    d4 = fminf(fmaxf((v), d3), d4);     \
    d3 = fminf(fmaxf((v), d2), d3);     \
    d2 = fminf(fmaxf((v), d1), d2);     \
    d1 = fminf(fmaxf((v), d0), d1);     \
    d0 = fminf((v), d0); }

#define CSW(p, q) { float lo_ = fminf(m##p, m##q); float hi_ = fmaxf(m##p, m##q); m##p = lo_; m##q = hi_; }

// merge my sorted-asc scalars with lane^mask partner's; keep 8 smallest sorted
#define MERGE8(mask) {                                   \
    float b0 = __shfl_xor(d0, (mask), 64);               \
    float b1 = __shfl_xor(d1, (mask), 64);               \
    float b2 = __shfl_xor(d2, (mask), 64);               \
    float b3 = __shfl_xor(d3, (mask), 64);               \
    float b4 = __shfl_xor(d4, (mask), 64);               \
    float b5 = __shfl_xor(d5, (mask), 64);               \
    float b6 = __shfl_xor(d6, (mask), 64);               \
    float b7 = __shfl_xor(d7, (mask), 64);               \
    float m0 = fminf(d0, b7), m1 = fminf(d1, b6);        \
    float m2 = fminf(d2, b5), m3 = fminf(d3, b4);        \
    float m4 = fminf(d4, b3), m5 = fminf(d5, b2);        \
    float m6 = fminf(d6, b1), m7 = fminf(d7, b0);        \
    CSW(0,4) CSW(1,5) CSW(2,6) CSW(3,7)                  \
    CSW(0,2) CSW(1,3) CSW(4,6) CSW(5,7)                  \
    CSW(0,1) CSW(2,3) CSW(4,5) CSW(6,7)                  \
    d0 = m0; d1 = m1; d2 = m2; d3 = m3;                  \
    d4 = m4; d5 = m5; d6 = m6; d7 = m7; }

// ---------------- K1: encoder MLP -> x, fp16-split arrays ----------------
__global__ __launch_bounds__(256) void k_encoder(
    const float* __restrict__ x_pfc,
    const float* __restrict__ W1, const float* __restrict__ b1,
    const float* __restrict__ W2, const float* __restrict__ b2,
    const float* __restrict__ W3, const float* __restrict__ b3,
    float* __restrict__ xo, _Float16* __restrict__ HL,
    _Float16* __restrict__ YH, _Float16* __restrict__ YL,
    _Float16* __restrict__ SQ2)
{
    __shared__ float sW1[DIN * 8];
    __shared__ float sb1[8];
    __shared__ float sW2[8 * 16];
    __shared__ float sb2[16];
    __shared__ float sW3[16 * 15];
    __shared__ float sb3[15];
    int t = threadIdx.x;
    for (int q = t; q < DIN * 8; q += 256) sW1[q] = W1[q];
    for (int q = t; q < 8; q += 256) sb1[q] = b1[q];
    for (int q = t; q < 8 * 16; q += 256) sW2[q] = W2[q];
    for (int q = t; q < 16; q += 256) sb2[q] = b2[q];
    for (int q = t; q < 16 * 15; q += 256) sW3[q] = W3[q];
    for (int q = t; q < 15; q += 256) sb3[q] = b3[q];
    __syncthreads();

    int i = blockIdx.x * 256 + t;
    float in[DIN];
#pragma unroll
    for (int d = 0; d < DIN; ++d) in[d] = x_pfc[i * DIN + d];

    float a1[8];
#pragma unroll
    for (int h = 0; h < 8; ++h) a1[h] = sb1[h];
#pragma unroll
    for (int d = 0; d < DIN; ++d) {
        float v = in[d];
#pragma unroll
        for (int h = 0; h < 8; ++h) a1[h] += v * sW1[d * 8 + h];
    }
#pragma unroll
    for (int h = 0; h < 8; ++h) a1[h] = silu(a1[h]);

    float a2[16];
#pragma unroll
    for (int h = 0; h < 16; ++h) a2[h] = sb2[h];
#pragma unroll
    for (int d = 0; d < 8; ++d) {
        float v = a1[d];
#pragma unroll
        for (int h = 0; h < 16; ++h) a2[h] += v * sW2[d * 16 + h];
    }
#pragma unroll
    for (int h = 0; h < 16; ++h) a2[h] = silu(a2[h]);

    float a3[15];
#pragma unroll
    for (int h = 0; h < 15; ++h) a3[h] = sb3[h];
#pragma unroll
    for (int d = 0; d < 16; ++d) {
        float v = a2[d];
#pragma unroll
        for (int h = 0; h < 15; ++h) a3[h] += v * sW3[d * 15 + h];
    }

    float xr[16];
#pragma unroll
    for (int h = 0; h < 15; ++h) xr[h] = a3[h];
    xr[15] = in[DIN - 1];

    float s = 0.0f;
#pragma unroll
    for (int d = 0; d < 16; ++d) s += xr[d] * xr[d];

#pragma unroll
    for (int d = 0; d < 16; ++d) {
        xo[i * 16 + d] = xr[d];
        _Float16 h = (_Float16)xr[d];
        _Float16 l = (_Float16)(xr[d] - (float)h);
        HL[(size_t)i * 32 + d] = h;
        HL[(size_t)i * 32 + 16 + d] = l;
        float y = -2.0f * xr[d];
        _Float16 yh = (_Float16)y;
        _Float16 yl = (_Float16)(y - (float)yh);
        YH[(size_t)i * 16 + d] = yh;
        YL[(size_t)i * 16 + d] = yl;
    }
    _Float16 sh = (_Float16)s;
    SQ2[(size_t)i * 2] = sh;
    SQ2[(size_t)i * 2 + 1] = (_Float16)(s - (float)sh);
}

// ---------------- K2: MFMA KNN top-8, two-pass, spill-free ----------------
// Block = 512 threads = 8 waves; i-tile = 16 columns (i0..i0+15), grid 1024.
// Wave w scans j in [w*2048,(w+1)*2048) in 16-j MFMA tiles:
//   C = mfma(A1,B1, mfma(A2,B2,0)) = sq[j] - 2*x_j.x_i  (fp16 hi/lo split)
// Pass 1: branchless scalar top-8 VALUES per lane (4 C rows per tile).
// Merge: cross-quad shuffle-bitonic + LDS across waves -> exact kth per i.
// Pass 2: bit-identical MFMA recompute, v <= kth -> append id (rare branch).
__global__ __launch_bounds__(512, 4) void k_knn(
    const _Float16* __restrict__ HL, const _Float16* __restrict__ YH,
    const _Float16* __restrict__ YL, const unsigned* __restrict__ SQD,
    int* __restrict__ knn_idx)
{
    __shared__ float wl[8 * 8 * 16];   // [k][w][m]
    __shared__ float kthv[16];
    __shared__ int cnt[16];
    __shared__ int cand[16 * 16];

    int t = threadIdx.x;
    int w = t >> 6;
    int lane = t & 63;
    int m = lane & 15;
    int kq = lane >> 4;
    int i0 = blockIdx.x * 16;

    if (t < 16) cnt[t] = 0;
    if (t < 256) cand[t] = i0 + (t >> 4);   // benign default (self)

    // B fragments: B[k][n], n = lane&15, k = (lane>>4)*8 + b
    int gi = i0 + m;
    half8 B1 = *(const half8*)(YH + (size_t)gi * 16 + (kq & 1) * 8);
    half8 B2;
    {
        HU r;
        if (kq < 2) {
            r.h = *(const half8*)(YL + (size_t)gi * 16 + kq * 8);
        } else {
            r.u.x = (kq == 2) ? 0x3C003C00u : 0u;   // 1.0h,1.0h
            r.u.y = 0u; r.u.z = 0u; r.u.w = 0u;
            // r.h is set via r.u
        }
        B2 = r.h;
    }

    float d0 = 3.4e38f, d1 = 3.4e38f, d2 = 3.4e38f, d3 = 3.4e38f;
    float d4 = 3.4e38f, d5 = 3.4e38f, d6 = 3.4e38f, d7 = 3.4e38f;

    const _Float16* aptr = HL + ((size_t)(w * 2048 + m)) * 32 + kq * 8;
    const unsigned* sqp = SQD + (w * 2048 + m);

    // ---- pass 1: values only, fully branchless ----
    for (int tt = 0; tt < 128; ++tt) {
        HU a1u; a1u.h = *(const half8*)aptr;
        unsigned sqd = *sqp;
        HU a2u;
        a2u.u.x = (kq < 2) ? a1u.u.x : ((kq == 2) ? sqd : 0u);
        a2u.u.y = (kq < 2) ? a1u.u.y : 0u;
        a2u.u.z = (kq < 2) ? a1u.u.z : 0u;
        a2u.u.w = (kq < 2) ? a1u.u.w : 0u;

        f32x4 c = {0.f, 0.f, 0.f, 0.f};
        c = __builtin_amdgcn_mfma_f32_16x16x32_f16(a2u.h, B2, c, 0, 0, 0);
        c = __builtin_amdgcn_mfma_f32_16x16x32_f16(a1u.h, B1, c, 0, 0, 0);

        INS8V(c.x); INS8V(c.y); INS8V(c.z); INS8V(c.w);

        aptr += 16 * 32;
        sqp += 16;
    }

    // ---- merge: cross-quad (lanes m, m+16, m+32, m+48 share column i0+m) ----
    MERGE8(16);
    MERGE8(32);
    if (kq == 0) {
        wl[(0 * 8 + w) * 16 + m] = d0;
        wl[(1 * 8 + w) * 16 + m] = d1;
        wl[(2 * 8 + w) * 16 + m] = d2;
        wl[(3 * 8 + w) * 16 + m] = d3;
        wl[(4 * 8 + w) * 16 + m] = d4;
        wl[(5 * 8 + w) * 16 + m] = d5;
        wl[(6 * 8 + w) * 16 + m] = d6;
        wl[(7 * 8 + w) * 16 + m] = d7;
    }
    __syncthreads();

    // ---- exact global kth per column i (16 lanes) ----
    if (t < 16) {
        float d0 = 3.4e38f, d1 = 3.4e38f, d2 = 3.4e38f, d3 = 3.4e38f;
        float d4 = 3.4e38f, d5 = 3.4e38f, d6 = 3.4e38f, d7 = 3.4e38f;
        for (int w2 = 0; w2 < 8; ++w2) {
#pragma unroll
            for (int k = 0; k < 8; ++k) {
                float v = wl[(k * 8 + w2) * 16 + t];
                INS8V(v);
            }
        }
        kthv[t] = d7;
    }
    __syncthreads();

    float kth = kthv[m];

    // ---- pass 2: bit-identical recompute, collect ids ----
    aptr = HL + ((size_t)(w * 2048 + m)) * 32 + kq * 8;
    sqp = SQD + (w * 2048 + m);
    int jbase = w * 2048 + kq * 4;

    for (int tt = 0; tt < 128; ++tt) {
        HU a1u; a1u.h = *(const half8*)aptr;
        unsigned sqd = *sqp;
        HU a2u;
        a2u.u.x = (kq < 2) ? a1u.u.x : ((kq == 2) ? sqd : 0u);
        a2u.u.y = (kq < 2) ? a1u.u.y : 0u;
        a2u.u.z = (kq < 2) ? a1u.u.z : 0u;
        a2u.u.w = (kq < 2) ? a1u.u.w : 0u;

        f32x4 c = {0.f, 0.f, 0.f, 0.f};
        c = __builtin_amdgcn_mfma_f32_16x16x32_f16(a2u.h, B2, c, 0, 0, 0);
        c = __builtin_amdgcn_mfma_f32_16x16x32_f16(a1u.h, B1, c, 0, 0, 0);

        bool h0 = c.x <= kth, h1 = c.y <= kth, h2 = c.z <= kth, h3 = c.w <= kth;
        if (__any(h0 | h1 | h2 | h3)) {
            int jr = jbase + tt * 16;
            if (h0) { int p = atomicAdd(&cnt[m], 1); if (p < 16) cand[m * 16 + p] = jr + 0; }
            if (h1) { int p = atomicAdd(&cnt[m], 1); if (p < 16) cand[m * 16 + p] = jr + 1; }
            if (h2) { int p = atomicAdd(&cnt[m], 1); if (p < 16) cand[m * 16 + p] = jr + 2; }
            if (h3) { int p = atomicAdd(&cnt[m], 1); if (p < 16) cand[m * 16 + p] = jr + 3; }
        }
        aptr += 16 * 32;
        sqp += 16;
    }
    __syncthreads();

    if (t < 16) {
#pragma unroll
        for (int k = 0; k < 8; ++k)
            knn_idx[(size_t)(i0 + t) * 8 + k] = cand[t * 16 + k];
    }
}

// ---------------- K3: edge conv + head MLP + output concat ----------------
__global__ __launch_bounds__(256) void k_head(
    const float* __restrict__ x, const int* __restrict__ knn_idx,
    const float* __restrict__ x_pfc,
    const float* __restrict__ We, const float* __restrict__ be,
    const float* __restrict__ Wf1, const float* __restrict__ bf1,
    const float* __restrict__ Wf2, const float* __restrict__ bf2,
    float* __restrict__ out)
{
    __shared__ float sWe[32 * 16];
    __shared__ float sbe[16];
    __shared__ float sWf1[16 * 32];
    __shared__ float sbf1[32];
    __shared__ float sWf2[32 * 16];
    __shared__ float sbf2[16];
    int t = threadIdx.x;
    for (int q = t; q < 32 * 16; q += 256) sWe[q] = We[q];
    for (int q = t; q < 16; q += 256) sbe[q] = be[q];
    for (int q = t; q < 16 * 32; q += 256) sWf1[q] = Wf1[q];
    for (int q = t; q < 32; q += 256) sbf1[q] = bf1[q];
    for (int q = t; q < 32 * 16; q += 256) sWf2[q] = Wf2[q];
    for (int q = t; q < 16; q += 256) sbf2[q] = bf2[q];
    __syncthreads();

    int i = blockIdx.x * 256 + t;
    float xi[16];
#pragma unroll
    for (int d = 0; d < 16; ++d) xi[d] = x[i * 16 + d];

    float accb[16];
#pragma unroll
    for (int h = 0; h < 16; ++h) accb[h] = sbe[h];
#pragma unroll
    for (int d = 0; d < 16; ++d) {
        float v = xi[d];
#pragma unroll
        for (int h = 0; h < 16; ++h) accb[h] += v * sWe[d * 16 + h];
    }

    float feats[16];
#pragma unroll
    for (int h = 0; h < 16; ++h) feats[h] = 0.0f;

    for (int e = 0; e < KNN; ++e) {
        int j = knn_idx[i * KNN + e];
        float xd[16];
        const float4* xjv = (const float4*)(x + (size_t)j * 16);
#pragma unroll
        for (int q = 0; q < 4; ++q) {
            float4 v = xjv[q];
            xd[q * 4 + 0] = v.x - xi[q * 4 + 0];
            xd[q * 4 + 1] = v.y - xi[q * 4 + 1];
            xd[q * 4 + 2] = v.z - xi[q * 4 + 2];
            xd[q * 4 + 3] = v.w - xi[q * 4 + 3];
        }
        float acc[16];
#pragma unroll
        for (int h = 0; h < 16; ++h) acc[h] = accb[h];
#pragma unroll
        for (int d = 0; d < 16; ++d) {
            float v = xd[d];
#pragma unroll
            for (int h = 0; h < 16; ++h) acc[h] += v * sWe[(16 + d) * 16 + h];
        }
#pragma unroll
        for (int h = 0; h < 16; ++h) feats[h] += silu(acc[h]);
    }
#pragma unroll
    for (int h = 0; h < 16; ++h) feats[h] *= (1.0f / KNN);

    float f1[32];
#pragma unroll
    for (int h = 0; h < 32; ++h) f1[h] = sbf1[h];
#pragma unroll
    for (int k = 0; k < 16; ++k) {
        float v = feats[k];
#pragma unroll
        for (int h = 0; h < 32; ++h) f1[h] += v * sWf1[k * 32 + h];
    }
#pragma unroll
    for (int h = 0; h < 32; ++h) f1[h] = silu(f1[h]);

    float f2[16];
#pragma unroll
    for (int h = 0; h < 16; ++h) f2[h] = sbf2[h];
#pragma unroll
    for (int k = 0; k < 32; ++k) {
        float v = f1[k];
#pragma unroll
        for (int h = 0; h < 16; ++h) f2[h] += v * sWf2[k * 16 + h];
    }

#pragma unroll
    for (int h = 0; h < 16; ++h) out[(size_t)i * 29 + h] = f2[h];
#pragma unroll
    for (int d = 0; d < DIN; ++d) out[(size_t)i * 29 + 16 + d] = x_pfc[i * DIN + d];
}

extern "C" void kernel_launch(void* const* d_in, const int* in_sizes, int n_in,
                              void* d_out, int out_size, void* d_ws, size_t ws_size,
                              hipStream_t stream)
{
    const float* x_pfc = (const float*)d_in[0];
    const float* W1 = (const float*)d_in[1];
    const float* b1 = (const float*)d_in[2];
    const float* W2 = (const float*)d_in[3];
    const float* b2 = (const float*)d_in[4];
    const float* W3 = (const float*)d_in[5];
    const float* b3 = (const float*)d_in[6];
    const float* We = (const float*)d_in[7];
    const float* be = (const float*)d_in[8];
    const float* Wf1 = (const float*)d_in[9];
    const float* bf1 = (const float*)d_in[10];
    const float* Wf2 = (const float*)d_in[11];
    const float* bf2 = (const float*)d_in[12];
    float* out = (float*)d_out;

    float* xw = (float*)d_ws;                       // N*16 f32
    int* idxw = (int*)(xw + (size_t)NPTS * 16);     // N*8 int
    _Float16* HLa = (_Float16*)(idxw + (size_t)NPTS * 8);  // N*32
    _Float16* YHa = HLa + (size_t)NPTS * 32;        // N*16
    _Float16* YLa = YHa + (size_t)NPTS * 16;        // N*16
    _Float16* SQ2a = YLa + (size_t)NPTS * 16;       // N*2

    hipLaunchKernelGGL(k_encoder, dim3(NPTS / 256), dim3(256), 0, stream,
                       x_pfc, W1, b1, W2, b2, W3, b3, xw, HLa, YHa, YLa, SQ2a);
    hipLaunchKernelGGL(k_knn, dim3(NPTS / 16), dim3(512), 0, stream,
                       HLa, YHa, YLa, (const unsigned*)SQ2a, idxw);
    hipLaunchKernelGGL(k_head, dim3(NPTS / 256), dim3(256), 0, stream,
                       xw, idxw, x_pfc, We, be, Wf1, bf1, Wf2, bf2, out);
}

// Round 6
// 285.774 us; speedup vs baseline: 2.6295x; 1.1615x over previous
//
#include <hip/hip_runtime.h>
#include <math.h>

#define NPTS 16384
#define DIN 13
#define KNN 8

typedef _Float16 half8 __attribute__((ext_vector_type(8)));
typedef float f32x4 __attribute__((ext_vector_type(4)));

union HU { uint4 u; half8 h; };

__device__ __forceinline__ float silu(float v) {
    return v / (1.0f + __expf(-v));
}

// branchless scalar top-8 insert (sorted ascending d0..d7).
// Invariant d0<=d1<=...<=d7 lets min(max(v,a),b) fuse to v_med3_f32.
#define MED3(v, a, b) __builtin_amdgcn_fmed3f((v), (a), (b))
#define INS8V(v) {                      \
    d7 = MED3((v), d6, d7);             \
    d6 = MED3((v), d5, d6);             \
    d5 = MED3((v), d4, d5);             \
    d4 = MED3((v), d3, d4);             \
    d3 = MED3((v), d2, d3);             \
    d2 = MED3((v), d1, d2);             \
    d1 = MED3((v), d0, d1);             \
    d0 = fminf((v), d0); }

#define CSW(p, q) { float lo_ = fminf(m##p, m##q); float hi_ = fmaxf(m##p, m##q); m##p = lo_; m##q = hi_; }

// merge my sorted-asc scalars with lane^mask partner's; keep 8 smallest sorted
#define MERGE8(mask) {                                   \
    float b0 = __shfl_xor(d0, (mask), 64);               \
    float b1 = __shfl_xor(d1, (mask), 64);               \
    float b2 = __shfl_xor(d2, (mask), 64);               \
    float b3 = __shfl_xor(d3, (mask), 64);               \
    float b4 = __shfl_xor(d4, (mask), 64);               \
    float b5 = __shfl_xor(d5, (mask), 64);               \
    float b6 = __shfl_xor(d6, (mask), 64);               \
    float b7 = __shfl_xor(d7, (mask), 64);               \
    float m0 = fminf(d0, b7), m1 = fminf(d1, b6);        \
    float m2 = fminf(d2, b5), m3 = fminf(d3, b4);        \
    float m4 = fminf(d4, b3), m5 = fminf(d5, b2);        \
    float m6 = fminf(d6, b1), m7 = fminf(d7, b0);        \
    CSW(0,4) CSW(1,5) CSW(2,6) CSW(3,7)                  \
    CSW(0,2) CSW(1,3) CSW(4,6) CSW(5,7)                  \
    CSW(0,1) CSW(2,3) CSW(4,5) CSW(6,7)                  \
    d0 = m0; d1 = m1; d2 = m2; d3 = m3;                  \
    d4 = m4; d5 = m5; d6 = m6; d7 = m7; }

// ---------------- K1: encoder MLP -> x, fp16-split arrays, sq fp32 -------
__global__ __launch_bounds__(64) void k_encoder(
    const float* __restrict__ x_pfc,
    const float* __restrict__ W1, const float* __restrict__ b1,
    const float* __restrict__ W2, const float* __restrict__ b2,
    const float* __restrict__ W3, const float* __restrict__ b3,
    float* __restrict__ xo, _Float16* __restrict__ HL,
    _Float16* __restrict__ YH, _Float16* __restrict__ YL,
    float* __restrict__ SQF)
{
    __shared__ float sW1[DIN * 8];
    __shared__ float sb1[8];
    __shared__ float sW2[8 * 16];
    __shared__ float sb2[16];
    __shared__ float sW3[16 * 15];
    __shared__ float sb3[15];
    int t = threadIdx.x;
    for (int q = t; q < DIN * 8; q += 64) sW1[q] = W1[q];
    for (int q = t; q < 8; q += 64) sb1[q] = b1[q];
    for (int q = t; q < 8 * 16; q += 64) sW2[q] = W2[q];
    for (int q = t; q < 16; q += 64) sb2[q] = b2[q];
    for (int q = t; q < 16 * 15; q += 64) sW3[q] = W3[q];
    for (int q = t; q < 15; q += 64) sb3[q] = b3[q];
    __syncthreads();

    int i = blockIdx.x * 64 + t;
    float in[DIN];
#pragma unroll
    for (int d = 0; d < DIN; ++d) in[d] = x_pfc[i * DIN + d];

    float a1[8];
#pragma unroll
    for (int h = 0; h < 8; ++h) a1[h] = sb1[h];
#pragma unroll
    for (int d = 0; d < DIN; ++d) {
        float v = in[d];
#pragma unroll
        for (int h = 0; h < 8; ++h) a1[h] += v * sW1[d * 8 + h];
    }
#pragma unroll
    for (int h = 0; h < 8; ++h) a1[h] = silu(a1[h]);

    float a2[16];
#pragma unroll
    for (int h = 0; h < 16; ++h) a2[h] = sb2[h];
#pragma unroll
    for (int d = 0; d < 8; ++d) {
        float v = a1[d];
#pragma unroll
        for (int h = 0; h < 16; ++h) a2[h] += v * sW2[d * 16 + h];
    }
#pragma unroll
    for (int h = 0; h < 16; ++h) a2[h] = silu(a2[h]);

    float a3[15];
#pragma unroll
    for (int h = 0; h < 15; ++h) a3[h] = sb3[h];
#pragma unroll
    for (int d = 0; d < 16; ++d) {
        float v = a2[d];
#pragma unroll
        for (int h = 0; h < 15; ++h) a3[h] += v * sW3[d * 15 + h];
    }

    float xr[16];
#pragma unroll
    for (int h = 0; h < 15; ++h) xr[h] = a3[h];
    xr[15] = in[DIN - 1];

    float s = 0.0f;
#pragma unroll
    for (int d = 0; d < 16; ++d) s += xr[d] * xr[d];

#pragma unroll
    for (int d = 0; d < 16; ++d) {
        xo[i * 16 + d] = xr[d];
        _Float16 h = (_Float16)xr[d];
        _Float16 l = (_Float16)(xr[d] - (float)h);
        HL[(size_t)i * 32 + d] = h;
        HL[(size_t)i * 32 + 16 + d] = l;
        float y = -2.0f * xr[d];
        _Float16 yh = (_Float16)y;
        _Float16 yl = (_Float16)(y - (float)yh);
        YH[(size_t)i * 16 + d] = yh;
        YL[(size_t)i * 16 + d] = yl;
    }
    SQF[i] = s;
}

// ---------------- K2: MFMA KNN top-8, two-pass, med3 selection -----------
// Block = 512 threads = 8 waves; i-tile = 16 columns, grid 1024.
// Wave w scans j in [w*2048,(w+1)*2048) in 16-j MFMA tiles:
//   c = mfma(A1,B1, mfma(A2,B2,0)) = -2*x_j.x_i  (fp16 hi/lo split)
//   v = c + sq[j]  (fp32 add, bit-identical in both passes)
// Pass 1: branchless scalar top-8 VALUES per lane (med3 chain).
// Merge: cross-quad shuffle-bitonic + LDS across waves -> exact kth per i.
// Pass 2: bit-identical recompute, v <= kth -> append id (rare branch).
__global__ __launch_bounds__(512, 8) void k_knn(
    const _Float16* __restrict__ HL, const _Float16* __restrict__ YH,
    const _Float16* __restrict__ YL, const float* __restrict__ SQF,
    int* __restrict__ knn_idx)
{
    __shared__ float wl[8 * 8 * 16];   // [k][w][m]
    __shared__ float kthv[16];
    __shared__ int cnt[16];
    __shared__ int cand[16 * 16];

    int t = threadIdx.x;
    int w = t >> 6;
    int lane = t & 63;
    int m = lane & 15;
    int kq = lane >> 4;
    int i0 = blockIdx.x * 16;

    if (t < 16) cnt[t] = 0;
    if (t < 256) cand[t] = i0 + (t >> 4);   // benign default (self)

    // B fragments: B[k][n], n = lane&15, k = (lane>>4)*8 + b
    int gi = i0 + m;
    half8 B1 = *(const half8*)(YH + (size_t)gi * 16 + (kq & 1) * 8);
    half8 B2;
    {
        HU r;
        if (kq < 2) {
            r.h = *(const half8*)(YL + (size_t)gi * 16 + kq * 8);
        } else {
            r.u.x = 0u; r.u.y = 0u; r.u.z = 0u; r.u.w = 0u;
        }
        B2 = r.h;
    }

    float d0 = 3.4e38f, d1 = 3.4e38f, d2 = 3.4e38f, d3 = 3.4e38f;
    float d4 = 3.4e38f, d5 = 3.4e38f, d6 = 3.4e38f, d7 = 3.4e38f;

    const _Float16* aptr = HL + ((size_t)(w * 2048 + m)) * 32 + kq * 8;
    const float* sqp = SQF + (w * 2048 + kq * 4);

    // ---- pass 1: values only, fully branchless ----
    for (int tt = 0; tt < 128; ++tt) {
        HU a1u; a1u.h = *(const half8*)aptr;
        float4 sv = *(const float4*)sqp;
        HU a2u;   // upper half (k=16..31, kq>=2) zeroed -> A2 = [h | 0]
        a2u.u.x = (kq < 2) ? a1u.u.x : 0u;
        a2u.u.y = (kq < 2) ? a1u.u.y : 0u;
        a2u.u.z = (kq < 2) ? a1u.u.z : 0u;
        a2u.u.w = (kq < 2) ? a1u.u.w : 0u;

        f32x4 c = {0.f, 0.f, 0.f, 0.f};
        c = __builtin_amdgcn_mfma_f32_16x16x32_f16(a2u.h, B2, c, 0, 0, 0);
        c = __builtin_amdgcn_mfma_f32_16x16x32_f16(a1u.h, B1, c, 0, 0, 0);

        float v0 = c.x + sv.x;
        float v1 = c.y + sv.y;
        float v2 = c.z + sv.z;
        float v3 = c.w + sv.w;
        INS8V(v0); INS8V(v1); INS8V(v2); INS8V(v3);

        aptr += 16 * 32;
        sqp += 16;
    }

    // ---- merge: cross-quad (lanes m, m+16, m+32, m+48 share column i0+m) ----
    MERGE8(16);
    MERGE8(32);
    if (kq == 0) {
        wl[(0 * 8 + w) * 16 + m] = d0;
        wl[(1 * 8 + w) * 16 + m] = d1;
        wl[(2 * 8 + w) * 16 + m] = d2;
        wl[(3 * 8 + w) * 16 + m] = d3;
        wl[(4 * 8 + w) * 16 + m] = d4;
        wl[(5 * 8 + w) * 16 + m] = d5;
        wl[(6 * 8 + w) * 16 + m] = d6;
        wl[(7 * 8 + w) * 16 + m] = d7;
    }
    __syncthreads();

    // ---- exact global kth per column i (16 lanes) ----
    if (t < 16) {
        float d0 = 3.4e38f, d1 = 3.4e38f, d2 = 3.4e38f, d3 = 3.4e38f;
        float d4 = 3.4e38f, d5 = 3.4e38f, d6 = 3.4e38f, d7 = 3.4e38f;
        for (int w2 = 0; w2 < 8; ++w2) {
#pragma unroll
            for (int k = 0; k < 8; ++k) {
                float v = wl[(k * 8 + w2) * 16 + t];
                INS8V(v);
            }
        }
        kthv[t] = d7;
    }
    __syncthreads();

    float kth = kthv[m];

    // ---- pass 2: bit-identical recompute, collect ids ----
    aptr = HL + ((size_t)(w * 2048 + m)) * 32 + kq * 8;
    sqp = SQF + (w * 2048 + kq * 4);
    int jbase = w * 2048 + kq * 4;

    for (int tt = 0; tt < 128; ++tt) {
        HU a1u; a1u.h = *(const half8*)aptr;
        float4 sv = *(const float4*)sqp;
        HU a2u;
        a2u.u.x = (kq < 2) ? a1u.u.x : 0u;
        a2u.u.y = (kq < 2) ? a1u.u.y : 0u;
        a2u.u.z = (kq < 2) ? a1u.u.z : 0u;
        a2u.u.w = (kq < 2) ? a1u.u.w : 0u;

        f32x4 c = {0.f, 0.f, 0.f, 0.f};
        c = __builtin_amdgcn_mfma_f32_16x16x32_f16(a2u.h, B2, c, 0, 0, 0);
        c = __builtin_amdgcn_mfma_f32_16x16x32_f16(a1u.h, B1, c, 0, 0, 0);

        float v0 = c.x + sv.x;
        float v1 = c.y + sv.y;
        float v2 = c.z + sv.z;
        float v3 = c.w + sv.w;

        bool h0 = v0 <= kth, h1 = v1 <= kth, h2 = v2 <= kth, h3 = v3 <= kth;
        if (__any(h0 | h1 | h2 | h3)) {
            int jr = jbase + tt * 16;
            if (h0) { int p = atomicAdd(&cnt[m], 1); if (p < 16) cand[m * 16 + p] = jr + 0; }
            if (h1) { int p = atomicAdd(&cnt[m], 1); if (p < 16) cand[m * 16 + p] = jr + 1; }
            if (h2) { int p = atomicAdd(&cnt[m], 1); if (p < 16) cand[m * 16 + p] = jr + 2; }
            if (h3) { int p = atomicAdd(&cnt[m], 1); if (p < 16) cand[m * 16 + p] = jr + 3; }
        }
        aptr += 16 * 32;
        sqp += 16;
    }
    __syncthreads();

    if (t < 16) {
#pragma unroll
        for (int k = 0; k < 8; ++k)
            knn_idx[(size_t)(i0 + t) * 8 + k] = cand[t * 16 + k];
    }
}

// ---------------- K3: edge conv + head MLP + output concat ----------------
__global__ __launch_bounds__(64) void k_head(
    const float* __restrict__ x, const int* __restrict__ knn_idx,
    const float* __restrict__ x_pfc,
    const float* __restrict__ We, const float* __restrict__ be,
    const float* __restrict__ Wf1, const float* __restrict__ bf1,
    const float* __restrict__ Wf2, const float* __restrict__ bf2,
    float* __restrict__ out)
{
    __shared__ float sWe[32 * 16];
    __shared__ float sbe[16];
    __shared__ float sWf1[16 * 32];
    __shared__ float sbf1[32];
    __shared__ float sWf2[32 * 16];
    __shared__ float sbf2[16];
    int t = threadIdx.x;
    for (int q = t; q < 32 * 16; q += 64) sWe[q] = We[q];
    for (int q = t; q < 16; q += 64) sbe[q] = be[q];
    for (int q = t; q < 16 * 32; q += 64) sWf1[q] = Wf1[q];
    for (int q = t; q < 32; q += 64) sbf1[q] = bf1[q];
    for (int q = t; q < 32 * 16; q += 64) sWf2[q] = Wf2[q];
    for (int q = t; q < 16; q += 64) sbf2[q] = bf2[q];
    __syncthreads();

    int i = blockIdx.x * 64 + t;
    float xi[16];
#pragma unroll
    for (int d = 0; d < 16; ++d) xi[d] = x[i * 16 + d];

    float accb[16];
#pragma unroll
    for (int h = 0; h < 16; ++h) accb[h] = sbe[h];
#pragma unroll
    for (int d = 0; d < 16; ++d) {
        float v = xi[d];
#pragma unroll
        for (int h = 0; h < 16; ++h) accb[h] += v * sWe[d * 16 + h];
    }

    float feats[16];
#pragma unroll
    for (int h = 0; h < 16; ++h) feats[h] = 0.0f;

    for (int e = 0; e < KNN; ++e) {
        int j = knn_idx[i * KNN + e];
        float xd[16];
        const float4* xjv = (const float4*)(x + (size_t)j * 16);
#pragma unroll
        for (int q = 0; q < 4; ++q) {
            float4 v = xjv[q];
            xd[q * 4 + 0] = v.x - xi[q * 4 + 0];
            xd[q * 4 + 1] = v.y - xi[q * 4 + 1];
            xd[q * 4 + 2] = v.z - xi[q * 4 + 2];
            xd[q * 4 + 3] = v.w - xi[q * 4 + 3];
        }
        float acc[16];
#pragma unroll
        for (int h = 0; h < 16; ++h) acc[h] = accb[h];
#pragma unroll
        for (int d = 0; d < 16; ++d) {
            float v = xd[d];
#pragma unroll
            for (int h = 0; h < 16; ++h) acc[h] += v * sWe[(16 + d) * 16 + h];
        }
#pragma unroll
        for (int h = 0; h < 16; ++h) feats[h] += silu(acc[h]);
    }
#pragma unroll
    for (int h = 0; h < 16; ++h) feats[h] *= (1.0f / KNN);

    float f1[32];
#pragma unroll
    for (int h = 0; h < 32; ++h) f1[h] = sbf1[h];
#pragma unroll
    for (int k = 0; k < 16; ++k) {
        float v = feats[k];
#pragma unroll
        for (int h = 0; h < 32; ++h) f1[h] += v * sWf1[k * 32 + h];
    }
#pragma unroll
    for (int h = 0; h < 32; ++h) f1[h] = silu(f1[h]);

    float f2[16];
#pragma unroll
    for (int h = 0; h < 16; ++h) f2[h] = sbf2[h];
#pragma unroll
    for (int k = 0; k < 32; ++k) {
        float v = f1[k];
#pragma unroll
        for (int h = 0; h < 16; ++h) f2[h] += v * sWf2[k * 16 + h];
    }

#pragma unroll
    for (int h = 0; h < 16; ++h) out[(size_t)i * 29 + h] = f2[h];
#pragma unroll
    for (int d = 0; d < DIN; ++d) out[(size_t)i * 29 + 16 + d] = x_pfc[i * DIN + d];
}

extern "C" void kernel_launch(void* const* d_in, const int* in_sizes, int n_in,
                              void* d_out, int out_size, void* d_ws, size_t ws_size,
                              hipStream_t stream)
{
    const float* x_pfc = (const float*)d_in[0];
    const float* W1 = (const float*)d_in[1];
    const float* b1 = (const float*)d_in[2];
    const float* W2 = (const float*)d_in[3];
    const float* b2 = (const float*)d_in[4];
    const float* W3 = (const float*)d_in[5];
    const float* b3 = (const float*)d_in[6];
    const float* We = (const float*)d_in[7];
    const float* be = (const float*)d_in[8];
    const float* Wf1 = (const float*)d_in[9];
    const float* bf1 = (const float*)d_in[10];
    const float* Wf2 = (const float*)d_in[11];
    const float* bf2 = (const float*)d_in[12];
    float* out = (float*)d_out;

    float* xw = (float*)d_ws;                       // N*16 f32
    int* idxw = (int*)(xw + (size_t)NPTS * 16);     // N*8 int
    _Float16* HLa = (_Float16*)(idxw + (size_t)NPTS * 8);  // N*32 f16
    _Float16* YHa = HLa + (size_t)NPTS * 32;        // N*16 f16
    _Float16* YLa = YHa + (size_t)NPTS * 16;        // N*16 f16
    float* SQFa = (float*)(YLa + (size_t)NPTS * 16); // N f32

    hipLaunchKernelGGL(k_encoder, dim3(NPTS / 64), dim3(64), 0, stream,
                       x_pfc, W1, b1, W2, b2, W3, b3, xw, HLa, YHa, YLa, SQFa);
    hipLaunchKernelGGL(k_knn, dim3(NPTS / 16), dim3(512), 0, stream,
                       HLa, YHa, YLa, SQFa, idxw);
    hipLaunchKernelGGL(k_head, dim3(NPTS / 64), dim3(64), 0, stream,
                       xw, idxw, x_pfc, We, be, Wf1, bf1, Wf2, bf2, out);
}

// Round 7
// 233.818 us; speedup vs baseline: 3.2137x; 1.2222x over previous
//
#include <hip/hip_runtime.h>
#include <math.h>

#define NPTS 16384
#define DIN 13
#define KNN 8

typedef _Float16 half8 __attribute__((ext_vector_type(8)));
typedef float f32x4 __attribute__((ext_vector_type(4)));
typedef float f32x16 __attribute__((ext_vector_type(16)));

__device__ __forceinline__ float silu(float v) {
    return v / (1.0f + __expf(-v));
}

// branchless scalar top-8 insert (sorted ascending d0..d7), med3 chain
#define MED3(v, a, b) __builtin_amdgcn_fmed3f((v), (a), (b))
#define INS8V(v) {                      \
    d7 = MED3((v), d6, d7);             \
    d6 = MED3((v), d5, d6);             \
    d5 = MED3((v), d4, d5);             \
    d4 = MED3((v), d3, d4);             \
    d3 = MED3((v), d2, d3);             \
    d2 = MED3((v), d1, d2);             \
    d1 = MED3((v), d0, d1);             \
    d0 = fminf((v), d0); }

#define CSW(p, q) { float lo_ = fminf(m##p, m##q); float hi_ = fmaxf(m##p, m##q); m##p = lo_; m##q = hi_; }

// merge my sorted-asc scalars with lane^mask partner's; keep 8 smallest sorted
#define MERGE8(mask) {                                   \
    float b0 = __shfl_xor(d0, (mask), 64);               \
    float b1 = __shfl_xor(d1, (mask), 64);               \
    float b2 = __shfl_xor(d2, (mask), 64);               \
    float b3 = __shfl_xor(d3, (mask), 64);               \
    float b4 = __shfl_xor(d4, (mask), 64);               \
    float b5 = __shfl_xor(d5, (mask), 64);               \
    float b6 = __shfl_xor(d6, (mask), 64);               \
    float b7 = __shfl_xor(d7, (mask), 64);               \
    float m0 = fminf(d0, b7), m1 = fminf(d1, b6);        \
    float m2 = fminf(d2, b5), m3 = fminf(d3, b4);        \
    float m4 = fminf(d4, b3), m5 = fminf(d5, b2);        \
    float m6 = fminf(d6, b1), m7 = fminf(d7, b0);        \
    CSW(0,4) CSW(1,5) CSW(2,6) CSW(3,7)                  \
    CSW(0,2) CSW(1,3) CSW(4,6) CSW(5,7)                  \
    CSW(0,1) CSW(2,3) CSW(4,5) CSW(6,7)                  \
    d0 = m0; d1 = m1; d2 = m2; d3 = m3;                  \
    d4 = m4; d5 = m5; d6 = m6; d7 = m7; }

// ---- K1: encoder MLP -> x(f32), H/L/YH/YL(f16 splits), sq(f32), accb ----
__global__ __launch_bounds__(64) void k_encoder(
    const float* __restrict__ x_pfc,
    const float* __restrict__ W1, const float* __restrict__ b1,
    const float* __restrict__ W2, const float* __restrict__ b2,
    const float* __restrict__ W3, const float* __restrict__ b3,
    const float* __restrict__ We, const float* __restrict__ be,
    float* __restrict__ xo, _Float16* __restrict__ H, _Float16* __restrict__ L,
    _Float16* __restrict__ YH, _Float16* __restrict__ YL,
    float* __restrict__ SQF, float* __restrict__ ACC)
{
    __shared__ float sW1[DIN * 8];
    __shared__ float sb1[8];
    __shared__ float sW2[8 * 16];
    __shared__ float sb2[16];
    __shared__ float sW3[16 * 15];
    __shared__ float sb3[15];
    __shared__ float sWe[16 * 16];   // top half of We (rows 0..15)
    __shared__ float sbe[16];
    int t = threadIdx.x;
    for (int q = t; q < DIN * 8; q += 64) sW1[q] = W1[q];
    for (int q = t; q < 8; q += 64) sb1[q] = b1[q];
    for (int q = t; q < 8 * 16; q += 64) sW2[q] = W2[q];
    for (int q = t; q < 16; q += 64) sb2[q] = b2[q];
    for (int q = t; q < 16 * 15; q += 64) sW3[q] = W3[q];
    for (int q = t; q < 15; q += 64) sb3[q] = b3[q];
    for (int q = t; q < 16 * 16; q += 64) sWe[q] = We[q];
    for (int q = t; q < 16; q += 64) sbe[q] = be[q];
    __syncthreads();

    int i = blockIdx.x * 64 + t;
    float in[DIN];
#pragma unroll
    for (int d = 0; d < DIN; ++d) in[d] = x_pfc[i * DIN + d];

    float a1[8];
#pragma unroll
    for (int h = 0; h < 8; ++h) a1[h] = sb1[h];
#pragma unroll
    for (int d = 0; d < DIN; ++d) {
        float v = in[d];
#pragma unroll
        for (int h = 0; h < 8; ++h) a1[h] += v * sW1[d * 8 + h];
    }
#pragma unroll
    for (int h = 0; h < 8; ++h) a1[h] = silu(a1[h]);

    float a2[16];
#pragma unroll
    for (int h = 0; h < 16; ++h) a2[h] = sb2[h];
#pragma unroll
    for (int d = 0; d < 8; ++d) {
        float v = a1[d];
#pragma unroll
        for (int h = 0; h < 16; ++h) a2[h] += v * sW2[d * 16 + h];
    }
#pragma unroll
    for (int h = 0; h < 16; ++h) a2[h] = silu(a2[h]);

    float a3[15];
#pragma unroll
    for (int h = 0; h < 15; ++h) a3[h] = sb3[h];
#pragma unroll
    for (int d = 0; d < 16; ++d) {
        float v = a2[d];
#pragma unroll
        for (int h = 0; h < 15; ++h) a3[h] += v * sW3[d * 15 + h];
    }

    float xr[16];
#pragma unroll
    for (int h = 0; h < 15; ++h) xr[h] = a3[h];
    xr[15] = in[DIN - 1];

    float s = 0.0f;
#pragma unroll
    for (int d = 0; d < 16; ++d) s += xr[d] * xr[d];

    float accb[16];
#pragma unroll
    for (int h = 0; h < 16; ++h) accb[h] = sbe[h];
#pragma unroll
    for (int d = 0; d < 16; ++d) {
        float v = xr[d];
#pragma unroll
        for (int h = 0; h < 16; ++h) accb[h] += v * sWe[d * 16 + h];
    }

#pragma unroll
    for (int d = 0; d < 16; ++d) {
        xo[i * 16 + d] = xr[d];
        _Float16 h = (_Float16)xr[d];
        _Float16 l = (_Float16)(xr[d] - (float)h);
        H[(size_t)i * 16 + d] = h;
        L[(size_t)i * 16 + d] = l;
        float y = -2.0f * xr[d];
        _Float16 yh = (_Float16)y;
        _Float16 yl = (_Float16)(y - (float)yh);
        YH[(size_t)i * 16 + d] = yh;
        YL[(size_t)i * 16 + d] = yl;
        ACC[(size_t)i * 16 + d] = accb[d];
    }
    SQF[i] = s;
}

// ---- K2: MFMA 32x32 KNN, two-pass ----
// Block = 512 thr = 8 waves; i-tile = 32 cols, grid 512.
// Per wave: j-chunk 2048 in 32-j tiles. C = 32x32x16 MFMA x3:
//   c = h.yh + l.yh + h.yl (fp32 acc), v = c + sq[j] (fp32).
// C layout: col=lane&31 (i, one list per lane), row=(reg&3)+8*(reg>>2)+4*(lane>>5).
__global__ __launch_bounds__(512, 4) void k_knn(
    const _Float16* __restrict__ H, const _Float16* __restrict__ L,
    const _Float16* __restrict__ YH, const _Float16* __restrict__ YL,
    const float* __restrict__ SQF, int* __restrict__ knn_idx)
{
    __shared__ float wl[8 * 8 * 32];   // [slot][wave][col] = 8 KB
    __shared__ float kthv[32];
    __shared__ int cnt[32];
    __shared__ int cand[32 * 16];

    int t = threadIdx.x;
    int w = t >> 6;
    int lane = t & 63;
    int r31 = lane & 31;
    int hh = lane >> 5;          // k-half for A/B frags, row offset for C
    int i0 = blockIdx.x * 32;

    if (t < 32) cnt[t] = 0;
    cand[t & 511] = i0 + ((t & 511) >> 4);   // benign default

    // B frags: B[k][n], n = lane&31 = col i, k = hh*8 + b
    int gi = i0 + r31;
    half8 B1 = *(const half8*)(YH + (size_t)gi * 16 + hh * 8);
    half8 B2 = *(const half8*)(YL + (size_t)gi * 16 + hh * 8);

    float d0 = 3.4e38f, d1 = 3.4e38f, d2 = 3.4e38f, d3 = 3.4e38f;
    float d4 = 3.4e38f, d5 = 3.4e38f, d6 = 3.4e38f, d7 = 3.4e38f;

    int jw = w * 2048;
    const _Float16* pH = H + ((size_t)(jw + r31)) * 16 + hh * 8;
    const _Float16* pL = L + ((size_t)(jw + r31)) * 16 + hh * 8;
    const float* pS = SQF + jw + 4 * hh;

    // ---- pass 1: values only ----
    for (int tt = 0; tt < 64; ++tt) {
        half8 Ah = *(const half8*)pH;
        half8 Al = *(const half8*)pL;
        f32x4 s0 = *(const f32x4*)(pS);
        f32x4 s1 = *(const f32x4*)(pS + 8);
        f32x4 s2 = *(const f32x4*)(pS + 16);
        f32x4 s3 = *(const f32x4*)(pS + 24);

        f32x16 c = {};
        c = __builtin_amdgcn_mfma_f32_32x32x16_f16(Ah, B1, c, 0, 0, 0);
        c = __builtin_amdgcn_mfma_f32_32x32x16_f16(Al, B1, c, 0, 0, 0);
        c = __builtin_amdgcn_mfma_f32_32x32x16_f16(Ah, B2, c, 0, 0, 0);

#pragma unroll
        for (int g = 0; g < 4; ++g) {
            f32x4 sg = (g == 0) ? s0 : (g == 1) ? s1 : (g == 2) ? s2 : s3;
#pragma unroll
            for (int q = 0; q < 4; ++q) {
                float v = c[g * 4 + q] + sg[q];
                INS8V(v);
            }
        }
        pH += 32 * 16;
        pL += 32 * 16;
        pS += 32;
    }

    // lanes r31 and r31+32 serve the same column -> merge
    MERGE8(32);
    if (lane < 32) {
        wl[(0 * 8 + w) * 32 + r31] = d0;
        wl[(1 * 8 + w) * 32 + r31] = d1;
        wl[(2 * 8 + w) * 32 + r31] = d2;
        wl[(3 * 8 + w) * 32 + r31] = d3;
        wl[(4 * 8 + w) * 32 + r31] = d4;
        wl[(5 * 8 + w) * 32 + r31] = d5;
        wl[(6 * 8 + w) * 32 + r31] = d6;
        wl[(7 * 8 + w) * 32 + r31] = d7;
    }
    __syncthreads();

    // exact global kth per column
    if (t < 32) {
        float d0 = 3.4e38f, d1 = 3.4e38f, d2 = 3.4e38f, d3 = 3.4e38f;
        float d4 = 3.4e38f, d5 = 3.4e38f, d6 = 3.4e38f, d7 = 3.4e38f;
        for (int w2 = 0; w2 < 8; ++w2) {
#pragma unroll
            for (int k = 0; k < 8; ++k) {
                float v = wl[(k * 8 + w2) * 32 + t];
                INS8V(v);
            }
        }
        kthv[t] = d7;
    }
    __syncthreads();

    float kth = kthv[r31];

    // ---- pass 2: bit-identical recompute, collect ids ----
    pH = H + ((size_t)(jw + r31)) * 16 + hh * 8;
    pL = L + ((size_t)(jw + r31)) * 16 + hh * 8;
    pS = SQF + jw + 4 * hh;

    for (int tt = 0; tt < 64; ++tt) {
        half8 Ah = *(const half8*)pH;
        half8 Al = *(const half8*)pL;
        f32x4 s0 = *(const f32x4*)(pS);
        f32x4 s1 = *(const f32x4*)(pS + 8);
        f32x4 s2 = *(const f32x4*)(pS + 16);
        f32x4 s3 = *(const f32x4*)(pS + 24);

        f32x16 c = {};
        c = __builtin_amdgcn_mfma_f32_32x32x16_f16(Ah, B1, c, 0, 0, 0);
        c = __builtin_amdgcn_mfma_f32_32x32x16_f16(Al, B1, c, 0, 0, 0);
        c = __builtin_amdgcn_mfma_f32_32x32x16_f16(Ah, B2, c, 0, 0, 0);

        float v[16];
#pragma unroll
        for (int g = 0; g < 4; ++g) {
            f32x4 sg = (g == 0) ? s0 : (g == 1) ? s1 : (g == 2) ? s2 : s3;
#pragma unroll
            for (int q = 0; q < 4; ++q) v[g * 4 + q] = c[g * 4 + q] + sg[q];
        }
        float vm = v[0];
#pragma unroll
        for (int r = 1; r < 16; ++r) vm = fminf(vm, v[r]);

        if (__any(vm <= kth)) {
            int j0 = jw + tt * 32;
#pragma unroll
            for (int r = 0; r < 16; ++r) {
                bool hit = v[r] <= kth;
                if (__any(hit)) {
                    if (hit) {
                        int row = (r & 3) + 8 * (r >> 2) + 4 * hh;
                        int p = atomicAdd(&cnt[r31], 1);
                        if (p < 16) cand[r31 * 16 + p] = j0 + row;
                    }
                }
            }
        }
        pH += 32 * 16;
        pL += 32 * 16;
        pS += 32;
    }
    __syncthreads();

    if (t < 32) {
#pragma unroll
        for (int k = 0; k < 8; ++k)
            knn_idx[(size_t)(i0 + t) * 8 + k] = cand[t * 16 + k];
    }
}

// ---- K3: edge conv + head MLP, 8 lanes per point ----
__global__ __launch_bounds__(256) void k_head(
    const float* __restrict__ x, const int* __restrict__ knn_idx,
    const float* __restrict__ x_pfc, const float* __restrict__ ACC,
    const float* __restrict__ We,
    const float* __restrict__ Wf1, const float* __restrict__ bf1,
    const float* __restrict__ Wf2, const float* __restrict__ bf2,
    float* __restrict__ out)
{
    __shared__ float sWe2[16 * 16];   // bottom half of We (rows 16..31)
    __shared__ float sWf1[16 * 32];
    __shared__ float sbf1[32];
    __shared__ float sWf2[32 * 16];
    __shared__ float sbf2[16];
    int t = threadIdx.x;
    for (int q = t; q < 16 * 16; q += 256) sWe2[q] = We[256 + q];
    for (int q = t; q < 16 * 32; q += 256) sWf1[q] = Wf1[q];
    for (int q = t; q < 32; q += 256) sbf1[q] = bf1[q];
    for (int q = t; q < 32 * 16; q += 256) sWf2[q] = Wf2[q];
    for (int q = t; q < 16; q += 256) sbf2[q] = bf2[q];
    __syncthreads();

    int i = blockIdx.x * 32 + (t >> 3);
    int e = t & 7;

    int j = knn_idx[(size_t)i * 8 + e];

    float xd[16];
    {
        const f32x4* xiv = (const f32x4*)(x + (size_t)i * 16);
        const f32x4* xjv = (const f32x4*)(x + (size_t)j * 16);
#pragma unroll
        for (int q = 0; q < 4; ++q) {
            f32x4 a = xjv[q], b = xiv[q];
#pragma unroll
            for (int r = 0; r < 4; ++r) xd[q * 4 + r] = a[r] - b[r];
        }
    }

    float acc[16];
    {
        const f32x4* av = (const f32x4*)(ACC + (size_t)i * 16);
#pragma unroll
        for (int q = 0; q < 4; ++q) {
            f32x4 a = av[q];
#pragma unroll
            for (int r = 0; r < 4; ++r) acc[q * 4 + r] = a[r];
        }
    }
#pragma unroll
    for (int d = 0; d < 16; ++d) {
        float v = xd[d];
#pragma unroll
        for (int h = 0; h < 16; ++h) acc[h] += v * sWe2[d * 16 + h];
    }

    float feats[16];
#pragma unroll
    for (int h = 0; h < 16; ++h) feats[h] = silu(acc[h]);

    // butterfly mean over the 8 lanes of this point
#pragma unroll
    for (int mask = 1; mask <= 4; mask <<= 1) {
#pragma unroll
        for (int h = 0; h < 16; ++h) feats[h] += __shfl_xor(feats[h], mask, 64);
    }
#pragma unroll
    for (int h = 0; h < 16; ++h) feats[h] *= 0.125f;

    float f1[32];
#pragma unroll
    for (int h = 0; h < 32; ++h) f1[h] = sbf1[h];
#pragma unroll
    for (int k = 0; k < 16; ++k) {
        float v = feats[k];
#pragma unroll
        for (int h = 0; h < 32; ++h) f1[h] += v * sWf1[k * 32 + h];
    }
#pragma unroll
    for (int h = 0; h < 32; ++h) f1[h] = silu(f1[h]);

    float f2[16];
#pragma unroll
    for (int h = 0; h < 16; ++h) f2[h] = sbf2[h];
#pragma unroll
    for (int k = 0; k < 32; ++k) {
        float v = f1[k];
#pragma unroll
        for (int h = 0; h < 16; ++h) f2[h] += v * sWf2[k * 16 + h];
    }

    // stores: lanes 0-3 write f2 (16 floats), lanes 4-7 write x_pfc (13)
    if (e < 4) {
#pragma unroll
        for (int q = 0; q < 4; ++q)
            out[(size_t)i * 29 + e * 4 + q] = f2[e * 4 + q];
    } else {
        int d00 = (e - 4) * 4;
#pragma unroll
        for (int q = 0; q < 4; ++q) {
            int d = d00 + q;
            if (d < DIN) out[(size_t)i * 29 + 16 + d] = x_pfc[i * DIN + d];
        }
    }
}

extern "C" void kernel_launch(void* const* d_in, const int* in_sizes, int n_in,
                              void* d_out, int out_size, void* d_ws, size_t ws_size,
                              hipStream_t stream)
{
    const float* x_pfc = (const float*)d_in[0];
    const float* W1 = (const float*)d_in[1];
    const float* b1 = (const float*)d_in[2];
    const float* W2 = (const float*)d_in[3];
    const float* b2 = (const float*)d_in[4];
    const float* W3 = (const float*)d_in[5];
    const float* b3 = (const float*)d_in[6];
    const float* We = (const float*)d_in[7];
    const float* be = (const float*)d_in[8];
    const float* Wf1 = (const float*)d_in[9];
    const float* bf1 = (const float*)d_in[10];
    const float* Wf2 = (const float*)d_in[11];
    const float* bf2 = (const float*)d_in[12];
    float* out = (float*)d_out;

    float* xw = (float*)d_ws;                         // N*16 f32
    int* idxw = (int*)(xw + (size_t)NPTS * 16);       // N*8 i32
    float* ACCa = (float*)(idxw + (size_t)NPTS * 8);  // N*16 f32
    _Float16* Ha = (_Float16*)(ACCa + (size_t)NPTS * 16);  // N*16 f16
    _Float16* La = Ha + (size_t)NPTS * 16;
    _Float16* YHa = La + (size_t)NPTS * 16;
    _Float16* YLa = YHa + (size_t)NPTS * 16;
    float* SQFa = (float*)(YLa + (size_t)NPTS * 16);  // N f32

    hipLaunchKernelGGL(k_encoder, dim3(NPTS / 64), dim3(64), 0, stream,
                       x_pfc, W1, b1, W2, b2, W3, b3, We, be,
                       xw, Ha, La, YHa, YLa, SQFa, ACCa);
    hipLaunchKernelGGL(k_knn, dim3(NPTS / 32), dim3(512), 0, stream,
                       Ha, La, YHa, YLa, SQFa, idxw);
    hipLaunchKernelGGL(k_head, dim3(NPTS / 32), dim3(256), 0, stream,
                       xw, idxw, x_pfc, ACCa, We, Wf1, bf1, Wf2, bf2, out);
}